// Round 20
// baseline (1142.261 us; speedup 1.0000x reference)
//
#include <hip/hip_runtime.h>

#define DIMN 8192
#define SEQ  1024
#define NHEAD 128

typedef __attribute__((ext_vector_type(8))) short bf16x8;
typedef __attribute__((ext_vector_type(4))) float f32x4;

#define MFMA16(a, b, c) __builtin_amdgcn_mfma_f32_16x16x32_bf16((a), (b), (c), 0, 0, 0)

__device__ __forceinline__ unsigned short f2bf(float f) {
  unsigned u = __float_as_uint(f);
  return (unsigned short)((u + 0x7FFFu + ((u >> 16) & 1u)) >> 16);
}
__device__ __forceinline__ unsigned pack2(float a, float b) {
  return (unsigned)f2bf(a) | ((unsigned)f2bf(b) << 16);
}
__device__ __forceinline__ unsigned pack2_rhu(float lo, float hi) {
  unsigned a = __float_as_uint(lo) + 0x8000u;
  unsigned b = __float_as_uint(hi) + 0x8000u;
  return (a >> 16) | (b & 0xFFFF0000u);
}
__device__ __forceinline__ unsigned short f2bf_rhu(float f) {
  return (unsigned short)((__float_as_uint(f) + 0x8000u) >> 16);
}
__device__ __forceinline__ void async_copy16(void* lds_dst, const void* gsrc) {
  __builtin_amdgcn_global_load_lds(
      (const __attribute__((address_space(1))) unsigned int*)gsrc,
      (__attribute__((address_space(3))) unsigned int*)lds_dst, 16, 0, 0);
}

// ---------------- shared device bodies ----------------

__device__ __forceinline__ void cvt_body(int i, const float* __restrict__ in,
                                         unsigned short* __restrict__ out) {
  const float4* p = (const float4*)in;
  float4 a = p[2 * i];
  float4 b = p[2 * i + 1];
  uint4 r;
  r.x = pack2(a.x, a.y);
  r.y = pack2(a.z, a.w);
  r.z = pack2(b.x, b.y);
  r.w = pack2(b.z, b.w);
  ((uint4*)out)[i] = r;
}

// LDS-free transpose into CHUNKED Wt. Chunk (ko,n) = W[8ko..8ko+7][n] as 8
// bf16 (16B) at byte offset (ko*8192+n)*16. GRID = 8192 blocks EXACTLY:
// ko = tbid & 1023 (1024 octets), n-group = tbid >> 10 (0..7, 1024 cols each).
// R19 CRASH: launched 16384 blocks -> n up to 16380 > 8191 -> OOB Wt writes.
__device__ __forceinline__ void transpose_chunk_body(
    int tbid, int t, const float* __restrict__ W, unsigned short* __restrict__ Wt) {
  const int ko = tbid & 1023;                       // k-octet 0..1023
  const int n = (tbid >> 10) * 1024 + t * 4;        // 4 consecutive n (0..8188)
  const float* src = W + (size_t)(ko * 8) * DIMN + n;
  float4 c[8];
#pragma unroll
  for (int j = 0; j < 8; ++j)
    c[j] = *(const float4*)(src + (size_t)j * DIMN);
  unsigned short* dst = Wt + ((size_t)ko * 8192 + n) * 8;
#pragma unroll
  for (int i = 0; i < 4; ++i) {
    uint4 r;
    r.x = pack2_rhu(((const float*)&c[0])[i], ((const float*)&c[1])[i]);
    r.y = pack2_rhu(((const float*)&c[2])[i], ((const float*)&c[3])[i]);
    r.z = pack2_rhu(((const float*)&c[4])[i], ((const float*)&c[5])[i]);
    r.w = pack2_rhu(((const float*)&c[6])[i], ((const float*)&c[7])[i]);
    ((uint4*)dst)[i] = r;
  }
}

// ---------------- standalone kernels ----------------

__global__ __launch_bounds__(256) void cvt_bf16_kernel(
    const float* __restrict__ in, unsigned short* __restrict__ out) {
  cvt_body(blockIdx.x * 256 + threadIdx.x, in, out);
}

__global__ __launch_bounds__(256) void transpose_chunk_kernel(
    const float* __restrict__ W, unsigned short* __restrict__ Wt) {
  transpose_chunk_body(blockIdx.x, threadIdx.x, W, Wt);
}

// cvt + transpose(wq) fused: both LDS-free -> no occupancy coupling.
__global__ __launch_bounds__(256) void cvtT_kernel(
    const float* __restrict__ x, unsigned short* __restrict__ xb,
    const float* __restrict__ W, unsigned short* __restrict__ Wt) {
  if (blockIdx.x < 4096)
    cvt_body(blockIdx.x * 256 + threadIdx.x, x, xb);
  else
    transpose_chunk_body(blockIdx.x - 4096, threadIdx.x, W, Wt);
}

// ---------------- pure-DMA BK=64 GEMM (R14/R16 verified: ~154us, 875 TF) ----
// Only the B-operand GLOBAL ADDRESS formula changed for the chunked Wt layout
// (LDS[row][p] <- chunk ko=p^(row&7), n = tile row — audit in R20 notes);
// the LDS image and compute are byte-identical to the verified version.
template <int WRITE_F32>
__global__ __launch_bounds__(256, 2) void gemm_dma(
    const unsigned short* __restrict__ A, const unsigned short* __restrict__ Wt,
    void* __restrict__ Cout, float out_scale) {
  __shared__ unsigned short smem[2 * 16384];
  const int t = threadIdx.x;
  const int l = t & 63;
  const int w = t >> 6;
  const int wm = w >> 1, wn = w & 1;
  const int logical = (blockIdx.x & 7) * 64 + (blockIdx.x >> 3);
  const int m0 = (logical & 7) * 128;
  const int n0 = (logical >> 3) * 128;
  const int rin = l >> 3;
  const int aslot = (l & 7) ^ rin;

  f32x4 acc[4][4];
#pragma unroll
  for (int mb = 0; mb < 4; ++mb)
#pragma unroll
    for (int nb = 0; nb < 4; ++nb) acc[mb][nb] = (f32x4){0.f, 0.f, 0.f, 0.f};

  const unsigned short* aptr = A + (size_t)(m0 + w * 32 + rin) * DIMN + aslot * 8;
  // chunked Wt: chunk (ko, n) at bf16-offset (ko*8192 + n)*8
  const unsigned short* bptr = Wt + ((size_t)aslot * 8192 + (n0 + w * 32 + rin)) * 8;

  auto stage = [&](int buf) {
    unsigned short* sa = &smem[buf * 16384];
    unsigned short* sb = sa + 8192;
#pragma unroll
    for (int i = 0; i < 4; ++i)
      async_copy16(&sa[(w * 32 + i * 8) * 64], aptr + (size_t)i * 8 * DIMN);
#pragma unroll
    for (int i = 0; i < 4; ++i)
      async_copy16(&sb[(w * 32 + i * 8) * 64], bptr + i * 64);  // n advances by 8
    aptr += 64;
    bptr += (size_t)8 * 8192 * 8;  // ko advances by 8 per BK=64 tile
  };
  auto compute = [&](int buf) {
    const unsigned short* la = &smem[buf * 16384];
    const unsigned short* lb = la + 8192;
#pragma unroll
    for (int kh = 0; kh < 2; ++kh) {
      bf16x8 af[4], bf[4];
#pragma unroll
      for (int mb = 0; mb < 4; ++mb) {
        int row = wm * 64 + mb * 16 + (l & 15);
        int sl = ((l >> 4) + kh * 4) ^ (row & 7);
        af[mb] = *(const bf16x8*)&la[row * 64 + sl * 8];
      }
#pragma unroll
      for (int nb = 0; nb < 4; ++nb) {
        int row = wn * 64 + nb * 16 + (l & 15);
        int sl = ((l >> 4) + kh * 4) ^ (row & 7);
        bf[nb] = *(const bf16x8*)&lb[row * 64 + sl * 8];
      }
      __builtin_amdgcn_s_setprio(1);
#pragma unroll
      for (int mb = 0; mb < 4; ++mb)
#pragma unroll
        for (int nb = 0; nb < 4; ++nb)
          acc[mb][nb] = MFMA16(af[mb], bf[nb], acc[mb][nb]);
      __builtin_amdgcn_s_setprio(0);
    }
  };

  stage(0);
  __syncthreads();
  int buf = 0;
  for (int kt = 0; kt < 128; ++kt) {
    if (kt < 127) stage(buf ^ 1);
    compute(buf);
    __syncthreads();
    buf ^= 1;
  }

#pragma unroll
  for (int mb = 0; mb < 4; ++mb)
#pragma unroll
    for (int nb = 0; nb < 4; ++nb)
#pragma unroll
      for (int r = 0; r < 4; ++r) {
        int rg = m0 + wm * 64 + mb * 16 + (l >> 4) * 4 + r;
        int cg = n0 + wn * 64 + nb * 16 + (l & 15);
        float vl = acc[mb][nb][r] * out_scale;
        if (WRITE_F32)
          ((float*)Cout)[(size_t)rg * DIMN + cg] = vl;
        else
          ((unsigned short*)Cout)[(size_t)rg * DIMN + cg] = f2bf(vl);
      }
}

// ---------------- fallback GEMM (R11 reg-staging) — ws too small for Wt ----
template <int WRITE_F32>
__global__ __launch_bounds__(256, 3) void gemm_fb(
    const unsigned short* __restrict__ A, const float* __restrict__ W,
    void* __restrict__ Cout, float out_scale) {
  __shared__ unsigned short smem[2 * 8192];
  const int t = threadIdx.x;
  const int l = t & 63;
  const int w = t >> 6;
  const int wm = w >> 1, wn = w & 1;
  const int logical = (blockIdx.x & 7) * 64 + (blockIdx.x >> 3);
  const int m0 = (logical & 7) * 128;
  const int n0 = (logical >> 3) * 128;
  const int arow = l >> 2;
  const int aslot = l & 3;
  const int bn = t & 127;
  const int bkb = (t >> 7) * 16;

  f32x4 acc[4][4];
#pragma unroll
  for (int mb = 0; mb < 4; ++mb)
#pragma unroll
    for (int nb = 0; nb < 4; ++nb) acc[mb][nb] = (f32x4){0.f, 0.f, 0.f, 0.f};

  float fb[16];
  const unsigned short* aptr = A + (size_t)(m0 + w * 32 + arow) * DIMN + aslot * 8;
  const float* wp = W + (size_t)bkb * DIMN + n0 + bn;

  auto load_B = [&]() {
#pragma unroll
    for (int i = 0; i < 16; ++i) fb[i] = wp[(size_t)i * DIMN];
    wp += (size_t)32 * DIMN;
  };
  auto write_B = [&](int buf) {
    unsigned short* bb = &smem[buf * 8192 + 4096];
    const int ps = (bn >> 1) & 3;
#pragma unroll
    for (int j = 0; j < 2; ++j) {
      int p = ((bkb >> 3) + j) ^ ps;
      uint4 val;
      val.x = pack2_rhu(fb[j * 8 + 0], fb[j * 8 + 1]);
      val.y = pack2_rhu(fb[j * 8 + 2], fb[j * 8 + 3]);
      val.z = pack2_rhu(fb[j * 8 + 4], fb[j * 8 + 5]);
      val.w = pack2_rhu(fb[j * 8 + 6], fb[j * 8 + 7]);
      *(uint4*)&bb[bn * 32 + p * 8] = val;
    }
  };
  auto stage_A = [&](int buf) {
#pragma unroll
    for (int i = 0; i < 2; ++i)
      async_copy16(&smem[buf * 8192 + (w * 32 + i * 16) * 32],
                   aptr + (size_t)i * 16 * DIMN);
    aptr += 32;
  };
  auto compute = [&](int buf) {
    const unsigned short* la = &smem[buf * 8192];
    const unsigned short* lb = la + 4096;
    bf16x8 af[4], bf[4];
#pragma unroll
    for (int mb = 0; mb < 4; ++mb) {
      int row = wm * 64 + mb * 16 + (l & 15);
      af[mb] = *(const bf16x8*)&la[row * 32 + (l >> 4) * 8];
    }
#pragma unroll
    for (int nb = 0; nb < 4; ++nb) {
      int row = wn * 64 + nb * 16 + (l & 15);
      int p = (l >> 4) ^ ((row >> 1) & 3);
      bf[nb] = *(const bf16x8*)&lb[row * 32 + p * 8];
    }
#pragma unroll
    for (int mb = 0; mb < 4; ++mb)
#pragma unroll
      for (int nb = 0; nb < 4; ++nb)
        acc[mb][nb] = MFMA16(af[mb], bf[nb], acc[mb][nb]);
  };

  load_B();
  stage_A(0);
  write_B(0);
  __syncthreads();
  int buf = 0;
  for (int kt = 0; kt < 256; ++kt) {
    if (kt < 255) {
      load_B();
      stage_A(buf ^ 1);
    }
    compute(buf);
    if (kt < 255) write_B(buf ^ 1);
    __syncthreads();
    buf ^= 1;
  }
#pragma unroll
  for (int mb = 0; mb < 4; ++mb)
#pragma unroll
    for (int nb = 0; nb < 4; ++nb)
#pragma unroll
      for (int r = 0; r < 4; ++r) {
        int rg = m0 + wm * 64 + mb * 16 + (l >> 4) * 4 + r;
        int cg = n0 + wn * 64 + nb * 16 + (l & 15);
        float vl = acc[mb][nb][r] * out_scale;
        if (WRITE_F32)
          ((float*)Cout)[(size_t)rg * DIMN + cg] = vl;
        else
          ((unsigned short*)Cout)[(size_t)rg * DIMN + cg] = f2bf(vl);
      }
}

// ---------------- fused flash attention (QBLK=128, R16-verified, serial) ----
__global__ __launch_bounds__(256) void attn_kernel(
    const unsigned short* __restrict__ q, const unsigned short* __restrict__ k,
    const unsigned short* __restrict__ v, unsigned short* __restrict__ o) {
  __shared__ unsigned short Qs[128 * 64];
  __shared__ unsigned short Ks[2][64 * 64];
  __shared__ unsigned short Vt[64 * 72];
  __shared__ unsigned short Ps[4][16 * 72];

  const int t = threadIdx.x, l = t & 63, w = t >> 6;
  const int logical = (blockIdx.x & 7) * 128 + (blockIdx.x >> 3);
  const int h = logical >> 3;
  const int q0 = (logical & 7) * 128;

  const int rin = l >> 3;
  const int aslot = (l & 7) ^ rin;
  const int skey = t >> 2;
  const int sd = (t & 3) * 16;

  const unsigned short* qsrc = q + (size_t)(q0 + w * 32 + rin) * DIMN + h * 64 + aslot * 8;
  const unsigned short* ksrc = k + (size_t)(w * 16 + rin) * DIMN + h * 64 + aslot * 8;
  const unsigned short* vsrc = v + (size_t)skey * DIMN + h * 64 + sd;

  auto kdma = [&](int buf, int kv) {
#pragma unroll
    for (int i = 0; i < 2; ++i)
      async_copy16(&Ks[buf][(w * 16 + i * 8) * 64],
                   ksrc + (size_t)(kv * 64 + i * 8) * DIMN);
  };
  uint4 va0, va1, vb0, vb1;
  auto vload = [&](uint4& r0, uint4& r1, int kv) {
    const unsigned short* p = vsrc + (size_t)(kv * 64) * DIMN;
    r0 = *(const uint4*)p;
    r1 = *(const uint4*)(p + 8);
  };
  auto vwrite = [&](const uint4& r0, const uint4& r1) {
    const unsigned short* cs = (const unsigned short*)&r0;
    const unsigned short* ds = (const unsigned short*)&r1;
#pragma unroll
    for (int j = 0; j < 8; ++j) {
      int row = sd + j;
      Vt[row * 72 + (((skey >> 3) ^ ((row >> 3) & 7)) << 3) + (skey & 7)] = cs[j];
    }
#pragma unroll
    for (int j = 0; j < 8; ++j) {
      int row = sd + 8 + j;
      Vt[row * 72 + (((skey >> 3) ^ ((row >> 3) & 7)) << 3) + (skey & 7)] = ds[j];
    }
  };

  float m_run[2][4], l_run[2][4];
  f32x4 oacc[2][4];
#pragma unroll
  for (int qh = 0; qh < 2; ++qh) {
#pragma unroll
    for (int r = 0; r < 4; ++r) { m_run[qh][r] = -1e30f; l_run[qh][r] = 0.f; }
#pragma unroll
    for (int db = 0; db < 4; ++db) oacc[qh][db] = (f32x4){0.f, 0.f, 0.f, 0.f};
  }

#pragma unroll
  for (int i = 0; i < 4; ++i)
    async_copy16(&Qs[(w * 32 + i * 8) * 64], qsrc + (size_t)(i * 8) * DIMN);
  kdma(0, 0);
  vload(va0, va1, 0);
  __syncthreads();

  bf16x8 qf[2][2];
#pragma unroll
  for (int qh = 0; qh < 2; ++qh)
#pragma unroll
    for (int kh = 0; kh < 2; ++kh) {
      int row = w * 32 + qh * 16 + (l & 15);
      int s = (l >> 4) + kh * 4;
      qf[qh][kh] = *(const bf16x8*)&Qs[row * 64 + (s ^ (row & 7)) * 8];
    }

  auto compute = [&](int kbuf) {
#pragma unroll
    for (int qh = 0; qh < 2; ++qh) {
      f32x4 sAcc[4];
#pragma unroll
      for (int nb = 0; nb < 4; ++nb) sAcc[nb] = (f32x4){0.f, 0.f, 0.f, 0.f};
#pragma unroll
      for (int kh = 0; kh < 2; ++kh) {
        bf16x8 kf[4];
#pragma unroll
        for (int nb = 0; nb < 4; ++nb) {
          int row = nb * 16 + (l & 15);
          int s = (l >> 4) + kh * 4;
          kf[nb] = *(const bf16x8*)&Ks[kbuf][row * 64 + (s ^ (row & 7)) * 8];
        }
        __builtin_amdgcn_s_setprio(1);
#pragma unroll
        for (int nb = 0; nb < 4; ++nb) sAcc[nb] = MFMA16(qf[qh][kh], kf[nb], sAcc[nb]);
        __builtin_amdgcn_s_setprio(0);
      }
      float sc[4], mx[4];
#pragma unroll
      for (int r = 0; r < 4; ++r) {
        float mv = fmaxf(fmaxf(sAcc[0][r], sAcc[1][r]), fmaxf(sAcc[2][r], sAcc[3][r]));
        mv = fmaxf(mv, __shfl_xor(mv, 1));
        mv = fmaxf(mv, __shfl_xor(mv, 2));
        mv = fmaxf(mv, __shfl_xor(mv, 4));
        mv = fmaxf(mv, __shfl_xor(mv, 8));
        float mn = fmaxf(m_run[qh][r], mv);
        sc[r] = __expf(m_run[qh][r] - mn);
        m_run[qh][r] = mn;
        mx[r] = mn;
      }
#pragma unroll
      for (int nb = 0; nb < 4; ++nb) {
        f32x4 sv = sAcc[nb];
#pragma unroll
        for (int r = 0; r < 4; ++r) sv[r] = __expf(sv[r] - mx[r]);
        sAcc[nb] = sv;
      }
#pragma unroll
      for (int r = 0; r < 4; ++r) {
        float ls = sAcc[0][r] + sAcc[1][r] + sAcc[2][r] + sAcc[3][r];
        ls += __shfl_xor(ls, 1);
        ls += __shfl_xor(ls, 2);
        ls += __shfl_xor(ls, 4);
        ls += __shfl_xor(ls, 8);
        l_run[qh][r] = l_run[qh][r] * sc[r] + ls;
      }
#pragma unroll
      for (int db = 0; db < 4; ++db) {
        f32x4 ov = oacc[qh][db];
#pragma unroll
        for (int r = 0; r < 4; ++r) ov[r] *= sc[r];
        oacc[qh][db] = ov;
      }
#pragma unroll
      for (int nb = 0; nb < 4; ++nb)
#pragma unroll
        for (int r = 0; r < 4; ++r)
          Ps[w][((l >> 4) * 4 + r) * 72 + nb * 16 + (l & 15)] = f2bf_rhu(sAcc[nb][r]);
#pragma unroll
      for (int kh = 0; kh < 2; ++kh) {
        bf16x8 pf = *(const bf16x8*)&Ps[w][(l & 15) * 72 + (l >> 4) * 8 + kh * 32];
        bf16x8 vf[4];
#pragma unroll
        for (int db = 0; db < 4; ++db) {
          int R = db * 16 + (l & 15);
          int s = (l >> 4) + kh * 4;
          vf[db] = *(const bf16x8*)&Vt[R * 72 + (s ^ ((R >> 3) & 7)) * 8];
        }
        __builtin_amdgcn_s_setprio(1);
#pragma unroll
        for (int db = 0; db < 4; ++db) oacc[qh][db] = MFMA16(pf, vf[db], oacc[qh][db]);
        __builtin_amdgcn_s_setprio(0);
      }
    }
  };

  for (int it = 0; it < 8; ++it) {
    int t0 = 2 * it;
    vwrite(va0, va1);
    __syncthreads();
    kdma(1, t0 + 1);
    vload(vb0, vb1, t0 + 1);
    compute(0);
    __syncthreads();
    vwrite(vb0, vb1);
    __syncthreads();
    if (it < 7) {
      kdma(0, t0 + 2);
      vload(va0, va1, t0 + 2);
    }
    compute(1);
    __syncthreads();
  }

#pragma unroll
  for (int qh = 0; qh < 2; ++qh)
#pragma unroll
    for (int db = 0; db < 4; ++db)
#pragma unroll
      for (int r = 0; r < 4; ++r) {
        float vl = oacc[qh][db][r] / l_run[qh][r];
        int rg = q0 + w * 32 + qh * 16 + (l >> 4) * 4 + r;
        int cg = h * 64 + db * 16 + (l & 15);
        o[(size_t)rg * DIMN + cg] = f2bf(vl);
      }
}

extern "C" void kernel_launch(void* const* d_in, const int* in_sizes, int n_in,
                              void* d_out, int out_size, void* d_ws, size_t ws_size,
                              hipStream_t stream) {
  const float* x  = (const float*)d_in[0];
  const float* wq = (const float*)d_in[1];
  const float* wk = (const float*)d_in[2];
  const float* wv = (const float*)d_in[3];
  const float* wo = (const float*)d_in[4];

  char* ws = (char*)d_ws;
  const size_t MB16 = (size_t)16 * 1024 * 1024;
  const size_t WT_BYTES = (size_t)DIMN * DIMN * 2;  // 128 MB
  const size_t NEED_DMA = 5 * MB16 + WT_BYTES;      // 208 MB

  if (ws_size >= NEED_DMA) {
    unsigned short* xb = (unsigned short*)(ws);
    unsigned short* qb = (unsigned short*)(ws + 1 * MB16);
    unsigned short* kb = (unsigned short*)(ws + 2 * MB16);
    unsigned short* vb = (unsigned short*)(ws + 3 * MB16);
    unsigned short* ab = (unsigned short*)(ws + 4 * MB16);
    unsigned short* Wt = (unsigned short*)(ws + 5 * MB16);

    cvtT_kernel<<<4096 + 8192, 256, 0, stream>>>(x, xb, wq, Wt);
    gemm_dma<0><<<512, 256, 0, stream>>>(xb, Wt, qb, 0.125f);  // softmax scale folded
    transpose_chunk_kernel<<<8192, 256, 0, stream>>>(wk, Wt);
    gemm_dma<0><<<512, 256, 0, stream>>>(xb, Wt, kb, 1.0f);
    transpose_chunk_kernel<<<8192, 256, 0, stream>>>(wv, Wt);
    gemm_dma<0><<<512, 256, 0, stream>>>(xb, Wt, vb, 1.0f);
    attn_kernel<<<1024, 256, 0, stream>>>(qb, kb, vb, ab);
    transpose_chunk_kernel<<<8192, 256, 0, stream>>>(wo, Wt);
    gemm_dma<1><<<512, 256, 0, stream>>>(ab, Wt, d_out, 1.0f);
  } else {
    unsigned short* xb = (unsigned short*)(ws);
    unsigned short* qb = (unsigned short*)(ws + 1 * MB16);
    unsigned short* kb = (unsigned short*)(ws + 2 * MB16);
    unsigned short* vb = (unsigned short*)(ws + 3 * MB16);
    unsigned short* ab = (unsigned short*)(ws + 4 * MB16);
    cvt_bf16_kernel<<<4096, 256, 0, stream>>>(x, xb);
    gemm_fb<0><<<512, 256, 0, stream>>>(xb, wq, qb, 0.125f);
    gemm_fb<0><<<512, 256, 0, stream>>>(xb, wk, kb, 1.0f);
    gemm_fb<0><<<512, 256, 0, stream>>>(xb, wv, vb, 1.0f);
    attn_kernel<<<1024, 256, 0, stream>>>(qb, kb, vb, ab);
    gemm_fb<1><<<512, 256, 0, stream>>>(ab, wo, d_out, 1.0f);
  }
}

// Round 21
// 1052.178 us; speedup vs baseline: 1.0856x; 1.0856x over previous
//
#include <hip/hip_runtime.h>

#define DIMN 8192
#define SEQ  1024
#define NHEAD 128

typedef __attribute__((ext_vector_type(8))) short bf16x8;
typedef __attribute__((ext_vector_type(4))) float f32x4;

#define MFMA16(a, b, c) __builtin_amdgcn_mfma_f32_16x16x32_bf16((a), (b), (c), 0, 0, 0)

__device__ __forceinline__ unsigned short f2bf(float f) {
  unsigned u = __float_as_uint(f);
  return (unsigned short)((u + 0x7FFFu + ((u >> 16) & 1u)) >> 16);
}
__device__ __forceinline__ unsigned pack2(float a, float b) {
  return (unsigned)f2bf(a) | ((unsigned)f2bf(b) << 16);
}
__device__ __forceinline__ unsigned pack2_rhu(float lo, float hi) {
  unsigned a = __float_as_uint(lo) + 0x8000u;
  unsigned b = __float_as_uint(hi) + 0x8000u;
  return (a >> 16) | (b & 0xFFFF0000u);
}
__device__ __forceinline__ unsigned short f2bf_rhu(float f) {
  return (unsigned short)((__float_as_uint(f) + 0x8000u) >> 16);
}
__device__ __forceinline__ void async_copy16(void* lds_dst, const void* gsrc) {
  __builtin_amdgcn_global_load_lds(
      (const __attribute__((address_space(1))) unsigned int*)gsrc,
      (__attribute__((address_space(3))) unsigned int*)lds_dst, 16, 0, 0);
}

// ---------------- shared device bodies ----------------

__device__ __forceinline__ void cvt_body(int i, const float* __restrict__ in,
                                         unsigned short* __restrict__ out) {
  const float4* p = (const float4*)in;
  float4 a = p[2 * i];
  float4 b = p[2 * i + 1];
  uint4 r;
  r.x = pack2(a.x, a.y);
  r.y = pack2(a.z, a.w);
  r.z = pack2(b.x, b.y);
  r.w = pack2(b.z, b.w);
  ((uint4*)out)[i] = r;
}

// LDS-free transpose into CHUNKED Wt (verified R20: passes, fast, coalesced).
// Chunk (ko,n) = W[8ko..8ko+7][n] as 8 bf16 (16B) at byte off (ko*8192+n)*16.
// GRID = 8192 blocks exactly (R19 crash was a 16384-block OOB launch).
__device__ __forceinline__ void transpose_chunk_body(
    int tbid, int t, const float* __restrict__ W, unsigned short* __restrict__ Wt) {
  const int ko = tbid & 1023;
  const int n = (tbid >> 10) * 1024 + t * 4;
  const float* src = W + (size_t)(ko * 8) * DIMN + n;
  float4 c[8];
#pragma unroll
  for (int j = 0; j < 8; ++j)
    c[j] = *(const float4*)(src + (size_t)j * DIMN);
  unsigned short* dst = Wt + ((size_t)ko * 8192 + n) * 8;
#pragma unroll
  for (int i = 0; i < 4; ++i) {
    uint4 r;
    r.x = pack2_rhu(((const float*)&c[0])[i], ((const float*)&c[1])[i]);
    r.y = pack2_rhu(((const float*)&c[2])[i], ((const float*)&c[3])[i]);
    r.z = pack2_rhu(((const float*)&c[4])[i], ((const float*)&c[5])[i]);
    r.w = pack2_rhu(((const float*)&c[6])[i], ((const float*)&c[7])[i]);
    ((uint4*)dst)[i] = r;
  }
}

// ---------------- standalone kernels ----------------

__global__ __launch_bounds__(256) void cvt_bf16_kernel(
    const float* __restrict__ in, unsigned short* __restrict__ out) {
  cvt_body(blockIdx.x * 256 + threadIdx.x, in, out);
}

__global__ __launch_bounds__(256) void transpose_chunk_kernel(
    const float* __restrict__ W, unsigned short* __restrict__ Wt) {
  transpose_chunk_body(blockIdx.x, threadIdx.x, W, Wt);
}

// cvt + transpose(wq) fused: both LDS-free -> no occupancy coupling.
__global__ __launch_bounds__(256) void cvtT_kernel(
    const float* __restrict__ x, unsigned short* __restrict__ xb,
    const float* __restrict__ W, unsigned short* __restrict__ Wt) {
  if (blockIdx.x < 4096)
    cvt_body(blockIdx.x * 256 + threadIdx.x, x, xb);
  else
    transpose_chunk_body(blockIdx.x - 4096, threadIdx.x, W, Wt);
}

// ---------------- pure-DMA BK=64 GEMM, octet-major B LDS ----------------
// R20 DIAGNOSIS: chunked-Wt B-DMA read 64 scattered 16B chunks/instr (128KB
// stride) -> request-rate/latency stall, 183us. FIX: B LDS image is now
// OCTET-MAJOR [p][n] (8 octets x 128 cols, same 16KB): DMA instr j reads
// chunks (kt*8 + (j>>1), n0 + (j&1)*64 + l) = 1KB FULLY CONTIGUOUS, LDS dest
// linear at j*1KB. Fragment read lb[(s*128+n)*8]: 16-lane groups read 256B
// contiguous; bank residue (n%8)*16 covers all 32 banks 2-way (free, m136).
// A-side staging/reads byte-identical to the R14/R16-verified kernel.
template <int WRITE_F32>
__global__ __launch_bounds__(256, 2) void gemm_dma(
    const unsigned short* __restrict__ A, const unsigned short* __restrict__ Wt,
    void* __restrict__ Cout, float out_scale) {
  __shared__ unsigned short smem[2 * 16384];
  const int t = threadIdx.x;
  const int l = t & 63;
  const int w = t >> 6;
  const int wm = w >> 1, wn = w & 1;
  const int logical = (blockIdx.x & 7) * 64 + (blockIdx.x >> 3);
  const int m0 = (logical & 7) * 128;
  const int n0 = (logical >> 3) * 128;
  const int rin = l >> 3;
  const int aslot = (l & 7) ^ rin;

  f32x4 acc[4][4];
#pragma unroll
  for (int mb = 0; mb < 4; ++mb)
#pragma unroll
    for (int nb = 0; nb < 4; ++nb) acc[mb][nb] = (f32x4){0.f, 0.f, 0.f, 0.f};

  const unsigned short* aptr = A + (size_t)(m0 + w * 32 + rin) * DIMN + aslot * 8;
  const unsigned short* bptr = Wt + (size_t)(n0 + l) * 8;  // lane-contiguous base

  auto stage = [&](int buf) {
    unsigned short* sa = &smem[buf * 16384];
    unsigned short* sb = sa + 8192;
#pragma unroll
    for (int i = 0; i < 4; ++i)
      async_copy16(&sa[(w * 32 + i * 8) * 64], aptr + (size_t)i * 8 * DIMN);
#pragma unroll
    for (int i = 0; i < 4; ++i) {
      int j = w * 4 + i;  // 16 instrs: octet p = j>>1, n-half = j&1
      async_copy16(&sb[j * 512],
                   bptr + ((size_t)(j >> 1) * 8192 + (j & 1) * 64) * 8);
    }
    aptr += 64;
    bptr += (size_t)8 * 8192 * 8;  // advance 8 k-octets per BK=64 tile
  };
  auto compute = [&](int buf) {
    const unsigned short* la = &smem[buf * 16384];
    const unsigned short* lb = la + 8192;
#pragma unroll
    for (int kh = 0; kh < 2; ++kh) {
      bf16x8 af[4], bf[4];
#pragma unroll
      for (int mb = 0; mb < 4; ++mb) {
        int row = wm * 64 + mb * 16 + (l & 15);
        int sl = ((l >> 4) + kh * 4) ^ (row & 7);
        af[mb] = *(const bf16x8*)&la[row * 64 + sl * 8];
      }
      int s = (l >> 4) + kh * 4;
#pragma unroll
      for (int nb = 0; nb < 4; ++nb) {
        int n = wn * 64 + nb * 16 + (l & 15);
        bf[nb] = *(const bf16x8*)&lb[(s * 128 + n) * 8];
      }
      __builtin_amdgcn_s_setprio(1);
#pragma unroll
      for (int mb = 0; mb < 4; ++mb)
#pragma unroll
        for (int nb = 0; nb < 4; ++nb)
          acc[mb][nb] = MFMA16(af[mb], bf[nb], acc[mb][nb]);
      __builtin_amdgcn_s_setprio(0);
    }
  };

  stage(0);
  __syncthreads();
  int buf = 0;
  for (int kt = 0; kt < 128; ++kt) {
    if (kt < 127) stage(buf ^ 1);
    compute(buf);
    __syncthreads();
    buf ^= 1;
  }

#pragma unroll
  for (int mb = 0; mb < 4; ++mb)
#pragma unroll
    for (int nb = 0; nb < 4; ++nb)
#pragma unroll
      for (int r = 0; r < 4; ++r) {
        int rg = m0 + wm * 64 + mb * 16 + (l >> 4) * 4 + r;
        int cg = n0 + wn * 64 + nb * 16 + (l & 15);
        float vl = acc[mb][nb][r] * out_scale;
        if (WRITE_F32)
          ((float*)Cout)[(size_t)rg * DIMN + cg] = vl;
        else
          ((unsigned short*)Cout)[(size_t)rg * DIMN + cg] = f2bf(vl);
      }
}

// ---------------- fallback GEMM (R11 reg-staging) — ws too small for Wt ----
template <int WRITE_F32>
__global__ __launch_bounds__(256, 3) void gemm_fb(
    const unsigned short* __restrict__ A, const float* __restrict__ W,
    void* __restrict__ Cout, float out_scale) {
  __shared__ unsigned short smem[2 * 8192];
  const int t = threadIdx.x;
  const int l = t & 63;
  const int w = t >> 6;
  const int wm = w >> 1, wn = w & 1;
  const int logical = (blockIdx.x & 7) * 64 + (blockIdx.x >> 3);
  const int m0 = (logical & 7) * 128;
  const int n0 = (logical >> 3) * 128;
  const int arow = l >> 2;
  const int aslot = l & 3;
  const int bn = t & 127;
  const int bkb = (t >> 7) * 16;

  f32x4 acc[4][4];
#pragma unroll
  for (int mb = 0; mb < 4; ++mb)
#pragma unroll
    for (int nb = 0; nb < 4; ++nb) acc[mb][nb] = (f32x4){0.f, 0.f, 0.f, 0.f};

  float fb[16];
  const unsigned short* aptr = A + (size_t)(m0 + w * 32 + arow) * DIMN + aslot * 8;
  const float* wp = W + (size_t)bkb * DIMN + n0 + bn;

  auto load_B = [&]() {
#pragma unroll
    for (int i = 0; i < 16; ++i) fb[i] = wp[(size_t)i * DIMN];
    wp += (size_t)32 * DIMN;
  };
  auto write_B = [&](int buf) {
    unsigned short* bb = &smem[buf * 8192 + 4096];
    const int ps = (bn >> 1) & 3;
#pragma unroll
    for (int j = 0; j < 2; ++j) {
      int p = ((bkb >> 3) + j) ^ ps;
      uint4 val;
      val.x = pack2_rhu(fb[j * 8 + 0], fb[j * 8 + 1]);
      val.y = pack2_rhu(fb[j * 8 + 2], fb[j * 8 + 3]);
      val.z = pack2_rhu(fb[j * 8 + 4], fb[j * 8 + 5]);
      val.w = pack2_rhu(fb[j * 8 + 6], fb[j * 8 + 7]);
      *(uint4*)&bb[bn * 32 + p * 8] = val;
    }
  };
  auto stage_A = [&](int buf) {
#pragma unroll
    for (int i = 0; i < 2; ++i)
      async_copy16(&smem[buf * 8192 + (w * 32 + i * 16) * 32],
                   aptr + (size_t)i * 16 * DIMN);
    aptr += 32;
  };
  auto compute = [&](int buf) {
    const unsigned short* la = &smem[buf * 8192];
    const unsigned short* lb = la + 4096;
    bf16x8 af[4], bf[4];
#pragma unroll
    for (int mb = 0; mb < 4; ++mb) {
      int row = wm * 64 + mb * 16 + (l & 15);
      af[mb] = *(const bf16x8*)&la[row * 32 + (l >> 4) * 8];
    }
#pragma unroll
    for (int nb = 0; nb < 4; ++nb) {
      int row = wn * 64 + nb * 16 + (l & 15);
      int p = (l >> 4) ^ ((row >> 1) & 3);
      bf[nb] = *(const bf16x8*)&lb[row * 32 + p * 8];
    }
#pragma unroll
    for (int mb = 0; mb < 4; ++mb)
#pragma unroll
      for (int nb = 0; nb < 4; ++nb)
        acc[mb][nb] = MFMA16(af[mb], bf[nb], acc[mb][nb]);
  };

  load_B();
  stage_A(0);
  write_B(0);
  __syncthreads();
  int buf = 0;
  for (int kt = 0; kt < 256; ++kt) {
    if (kt < 255) {
      load_B();
      stage_A(buf ^ 1);
    }
    compute(buf);
    if (kt < 255) write_B(buf ^ 1);
    __syncthreads();
    buf ^= 1;
  }
#pragma unroll
  for (int mb = 0; mb < 4; ++mb)
#pragma unroll
    for (int nb = 0; nb < 4; ++nb)
#pragma unroll
      for (int r = 0; r < 4; ++r) {
        int rg = m0 + wm * 64 + mb * 16 + (l >> 4) * 4 + r;
        int cg = n0 + wn * 64 + nb * 16 + (l & 15);
        float vl = acc[mb][nb][r] * out_scale;
        if (WRITE_F32)
          ((float*)Cout)[(size_t)rg * DIMN + cg] = vl;
        else
          ((unsigned short*)Cout)[(size_t)rg * DIMN + cg] = f2bf(vl);
      }
}

// ---------------- fused flash attention (QBLK=128, R16-verified, serial) ----
__global__ __launch_bounds__(256) void attn_kernel(
    const unsigned short* __restrict__ q, const unsigned short* __restrict__ k,
    const unsigned short* __restrict__ v, unsigned short* __restrict__ o) {
  __shared__ unsigned short Qs[128 * 64];
  __shared__ unsigned short Ks[2][64 * 64];
  __shared__ unsigned short Vt[64 * 72];
  __shared__ unsigned short Ps[4][16 * 72];

  const int t = threadIdx.x, l = t & 63, w = t >> 6;
  const int logical = (blockIdx.x & 7) * 128 + (blockIdx.x >> 3);
  const int h = logical >> 3;
  const int q0 = (logical & 7) * 128;

  const int rin = l >> 3;
  const int aslot = (l & 7) ^ rin;
  const int skey = t >> 2;
  const int sd = (t & 3) * 16;

  const unsigned short* qsrc = q + (size_t)(q0 + w * 32 + rin) * DIMN + h * 64 + aslot * 8;
  const unsigned short* ksrc = k + (size_t)(w * 16 + rin) * DIMN + h * 64 + aslot * 8;
  const unsigned short* vsrc = v + (size_t)skey * DIMN + h * 64 + sd;

  auto kdma = [&](int buf, int kv) {
#pragma unroll
    for (int i = 0; i < 2; ++i)
      async_copy16(&Ks[buf][(w * 16 + i * 8) * 64],
                   ksrc + (size_t)(kv * 64 + i * 8) * DIMN);
  };
  uint4 va0, va1, vb0, vb1;
  auto vload = [&](uint4& r0, uint4& r1, int kv) {
    const unsigned short* p = vsrc + (size_t)(kv * 64) * DIMN;
    r0 = *(const uint4*)p;
    r1 = *(const uint4*)(p + 8);
  };
  auto vwrite = [&](const uint4& r0, const uint4& r1) {
    const unsigned short* cs = (const unsigned short*)&r0;
    const unsigned short* ds = (const unsigned short*)&r1;
#pragma unroll
    for (int j = 0; j < 8; ++j) {
      int row = sd + j;
      Vt[row * 72 + (((skey >> 3) ^ ((row >> 3) & 7)) << 3) + (skey & 7)] = cs[j];
    }
#pragma unroll
    for (int j = 0; j < 8; ++j) {
      int row = sd + 8 + j;
      Vt[row * 72 + (((skey >> 3) ^ ((row >> 3) & 7)) << 3) + (skey & 7)] = ds[j];
    }
  };

  float m_run[2][4], l_run[2][4];
  f32x4 oacc[2][4];
#pragma unroll
  for (int qh = 0; qh < 2; ++qh) {
#pragma unroll
    for (int r = 0; r < 4; ++r) { m_run[qh][r] = -1e30f; l_run[qh][r] = 0.f; }
#pragma unroll
    for (int db = 0; db < 4; ++db) oacc[qh][db] = (f32x4){0.f, 0.f, 0.f, 0.f};
  }

#pragma unroll
  for (int i = 0; i < 4; ++i)
    async_copy16(&Qs[(w * 32 + i * 8) * 64], qsrc + (size_t)(i * 8) * DIMN);
  kdma(0, 0);
  vload(va0, va1, 0);
  __syncthreads();

  bf16x8 qf[2][2];
#pragma unroll
  for (int qh = 0; qh < 2; ++qh)
#pragma unroll
    for (int kh = 0; kh < 2; ++kh) {
      int row = w * 32 + qh * 16 + (l & 15);
      int s = (l >> 4) + kh * 4;
      qf[qh][kh] = *(const bf16x8*)&Qs[row * 64 + (s ^ (row & 7)) * 8];
    }

  auto compute = [&](int kbuf) {
#pragma unroll
    for (int qh = 0; qh < 2; ++qh) {
      f32x4 sAcc[4];
#pragma unroll
      for (int nb = 0; nb < 4; ++nb) sAcc[nb] = (f32x4){0.f, 0.f, 0.f, 0.f};
#pragma unroll
      for (int kh = 0; kh < 2; ++kh) {
        bf16x8 kf[4];
#pragma unroll
        for (int nb = 0; nb < 4; ++nb) {
          int row = nb * 16 + (l & 15);
          int s = (l >> 4) + kh * 4;
          kf[nb] = *(const bf16x8*)&Ks[kbuf][row * 64 + (s ^ (row & 7)) * 8];
        }
        __builtin_amdgcn_s_setprio(1);
#pragma unroll
        for (int nb = 0; nb < 4; ++nb) sAcc[nb] = MFMA16(qf[qh][kh], kf[nb], sAcc[nb]);
        __builtin_amdgcn_s_setprio(0);
      }
      float sc[4], mx[4];
#pragma unroll
      for (int r = 0; r < 4; ++r) {
        float mv = fmaxf(fmaxf(sAcc[0][r], sAcc[1][r]), fmaxf(sAcc[2][r], sAcc[3][r]));
        mv = fmaxf(mv, __shfl_xor(mv, 1));
        mv = fmaxf(mv, __shfl_xor(mv, 2));
        mv = fmaxf(mv, __shfl_xor(mv, 4));
        mv = fmaxf(mv, __shfl_xor(mv, 8));
        float mn = fmaxf(m_run[qh][r], mv);
        sc[r] = __expf(m_run[qh][r] - mn);
        m_run[qh][r] = mn;
        mx[r] = mn;
      }
#pragma unroll
      for (int nb = 0; nb < 4; ++nb) {
        f32x4 sv = sAcc[nb];
#pragma unroll
        for (int r = 0; r < 4; ++r) sv[r] = __expf(sv[r] - mx[r]);
        sAcc[nb] = sv;
      }
#pragma unroll
      for (int r = 0; r < 4; ++r) {
        float ls = sAcc[0][r] + sAcc[1][r] + sAcc[2][r] + sAcc[3][r];
        ls += __shfl_xor(ls, 1);
        ls += __shfl_xor(ls, 2);
        ls += __shfl_xor(ls, 4);
        ls += __shfl_xor(ls, 8);
        l_run[qh][r] = l_run[qh][r] * sc[r] + ls;
      }
#pragma unroll
      for (int db = 0; db < 4; ++db) {
        f32x4 ov = oacc[qh][db];
#pragma unroll
        for (int r = 0; r < 4; ++r) ov[r] *= sc[r];
        oacc[qh][db] = ov;
      }
#pragma unroll
      for (int nb = 0; nb < 4; ++nb)
#pragma unroll
        for (int r = 0; r < 4; ++r)
          Ps[w][((l >> 4) * 4 + r) * 72 + nb * 16 + (l & 15)] = f2bf_rhu(sAcc[nb][r]);
#pragma unroll
      for (int kh = 0; kh < 2; ++kh) {
        bf16x8 pf = *(const bf16x8*)&Ps[w][(l & 15) * 72 + (l >> 4) * 8 + kh * 32];
        bf16x8 vf[4];
#pragma unroll
        for (int db = 0; db < 4; ++db) {
          int R = db * 16 + (l & 15);
          int s = (l >> 4) + kh * 4;
          vf[db] = *(const bf16x8*)&Vt[R * 72 + (s ^ ((R >> 3) & 7)) * 8];
        }
        __builtin_amdgcn_s_setprio(1);
#pragma unroll
        for (int db = 0; db < 4; ++db) oacc[qh][db] = MFMA16(pf, vf[db], oacc[qh][db]);
        __builtin_amdgcn_s_setprio(0);
      }
    }
  };

  for (int it = 0; it < 8; ++it) {
    int t0 = 2 * it;
    vwrite(va0, va1);
    __syncthreads();
    kdma(1, t0 + 1);
    vload(vb0, vb1, t0 + 1);
    compute(0);
    __syncthreads();
    vwrite(vb0, vb1);
    __syncthreads();
    if (it < 7) {
      kdma(0, t0 + 2);
      vload(va0, va1, t0 + 2);
    }
    compute(1);
    __syncthreads();
  }

#pragma unroll
  for (int qh = 0; qh < 2; ++qh)
#pragma unroll
    for (int db = 0; db < 4; ++db)
#pragma unroll
      for (int r = 0; r < 4; ++r) {
        float vl = oacc[qh][db][r] / l_run[qh][r];
        int rg = q0 + w * 32 + qh * 16 + (l >> 4) * 4 + r;
        int cg = h * 64 + db * 16 + (l & 15);
        o[(size_t)rg * DIMN + cg] = f2bf(vl);
      }
}

extern "C" void kernel_launch(void* const* d_in, const int* in_sizes, int n_in,
                              void* d_out, int out_size, void* d_ws, size_t ws_size,
                              hipStream_t stream) {
  const float* x  = (const float*)d_in[0];
  const float* wq = (const float*)d_in[1];
  const float* wk = (const float*)d_in[2];
  const float* wv = (const float*)d_in[3];
  const float* wo = (const float*)d_in[4];

  char* ws = (char*)d_ws;
  const size_t MB16 = (size_t)16 * 1024 * 1024;
  const size_t WT_BYTES = (size_t)DIMN * DIMN * 2;  // 128 MB
  const size_t NEED_DMA = 5 * MB16 + WT_BYTES;      // 208 MB

  if (ws_size >= NEED_DMA) {
    unsigned short* xb = (unsigned short*)(ws);
    unsigned short* qb = (unsigned short*)(ws + 1 * MB16);
    unsigned short* kb = (unsigned short*)(ws + 2 * MB16);
    unsigned short* vb = (unsigned short*)(ws + 3 * MB16);
    unsigned short* ab = (unsigned short*)(ws + 4 * MB16);
    unsigned short* Wt = (unsigned short*)(ws + 5 * MB16);

    cvtT_kernel<<<4096 + 8192, 256, 0, stream>>>(x, xb, wq, Wt);
    gemm_dma<0><<<512, 256, 0, stream>>>(xb, Wt, qb, 0.125f);  // softmax scale folded
    transpose_chunk_kernel<<<8192, 256, 0, stream>>>(wk, Wt);
    gemm_dma<0><<<512, 256, 0, stream>>>(xb, Wt, kb, 1.0f);
    transpose_chunk_kernel<<<8192, 256, 0, stream>>>(wv, Wt);
    gemm_dma<0><<<512, 256, 0, stream>>>(xb, Wt, vb, 1.0f);
    attn_kernel<<<1024, 256, 0, stream>>>(qb, kb, vb, ab);
    transpose_chunk_kernel<<<8192, 256, 0, stream>>>(wo, Wt);
    gemm_dma<1><<<512, 256, 0, stream>>>(ab, Wt, d_out, 1.0f);
  } else {
    unsigned short* xb = (unsigned short*)(ws);
    unsigned short* qb = (unsigned short*)(ws + 1 * MB16);
    unsigned short* kb = (unsigned short*)(ws + 2 * MB16);
    unsigned short* vb = (unsigned short*)(ws + 3 * MB16);
    unsigned short* ab = (unsigned short*)(ws + 4 * MB16);
    cvt_bf16_kernel<<<4096, 256, 0, stream>>>(x, xb);
    gemm_fb<0><<<512, 256, 0, stream>>>(xb, wq, qb, 0.125f);
    gemm_fb<0><<<512, 256, 0, stream>>>(xb, wk, kb, 1.0f);
    gemm_fb<0><<<512, 256, 0, stream>>>(xb, wv, vb, 1.0f);
    attn_kernel<<<1024, 256, 0, stream>>>(qb, kb, vb, ab);
    gemm_fb<1><<<512, 256, 0, stream>>>(ab, wo, d_out, 1.0f);
  }
}